// Round 1
// baseline (504.431 us; speedup 1.0000x reference)
//
#include <hip/hip_runtime.h>
#include <hip/hip_bf16.h>
#include <math.h>

#define HIDDEN 2048
#define NH 16
#define HD 128
#define NB 2
#define SEQ 2048
#define K_DIM 2048

typedef unsigned int u32;
typedef unsigned short ushort_t;
typedef __bf16 bf16x8 __attribute__((ext_vector_type(8)));
typedef float f32x4 __attribute__((ext_vector_type(4)));
typedef ushort_t u16x8 __attribute__((ext_vector_type(8)));

// ---------- fp32 -> (bf16 hi, bf16 lo) split, RNE both halves ----------
__device__ __forceinline__ void split1(float x, unsigned short& h, unsigned short& l) {
    u32 u = __float_as_uint(x);
    u32 hr = (u + 0x7FFFu + ((u >> 16) & 1u)) >> 16;
    h = (unsigned short)hr;
    float r = x - __uint_as_float(hr << 16);
    u32 u2 = __float_as_uint(r);
    l = (unsigned short)((u2 + 0x7FFFu + ((u2 >> 16) & 1u)) >> 16);
}

__device__ __forceinline__ ushort_t bf16r(float x) {
    u32 u = __float_as_uint(x);
    return (ushort_t)((u + 0x7FFFu + ((u >> 16) & 1u)) >> 16);
}

__device__ __forceinline__ void gl_lds16(const void* g, void* l) {
    __builtin_amdgcn_global_load_lds(
        (const __attribute__((address_space(1))) u32*)g,
        (__attribute__((address_space(3))) u32*)l, 16, 0, 0);
}

// ==================== RoPE tables (double-precision trig) ====================
__global__ void k_rope_tables(float* __restrict__ ct, float* __restrict__ st) {
    int idx = blockIdx.x * 256 + threadIdx.x;   // exactly SEQ*64 threads
    int s = idx >> 6, d = idx & 63;
    double inv = pow(10000.0, -(double)d * (1.0 / 64.0));
    double ang = (double)s * inv;
    ct[idx] = (float)cos(ang);
    st[idx] = (float)sin(ang);
}

// ==================== fused fp32 -> bf16 (hi only) for X, Wq, Wk, Wv ========
#define XG 2097152   // X float4 groups
#define WG 1048576   // W float4 groups
__global__ void k_cvt_all(const float4* __restrict__ X, const float4* __restrict__ W0,
                          const float4* __restrict__ W1, const float4* __restrict__ W2,
                          ushort4* __restrict__ Xh, ushort4* __restrict__ H0,
                          ushort4* __restrict__ H1, ushort4* __restrict__ H2) {
    int idx = blockIdx.x * 256 + threadIdx.x;   // XG + 3*WG threads
    const float4* src;
    ushort4* dst;
    int off;
    if (idx < XG) { src = X; dst = Xh; off = idx; }
    else {
        int t = idx - XG;
        int m = t >> 20;        // WG = 2^20
        off = t & (WG - 1);
        src = (m == 0) ? W0 : (m == 1) ? W1 : W2;
        dst = (m == 0) ? H0 : (m == 1) ? H1 : H2;
    }
    float4 x = src[off];
    ushort4 h;
    h.x = bf16r(x.x); h.y = bf16r(x.y); h.z = bf16r(x.z); h.w = bf16r(x.w);
    dst[off] = h;
}

// ==================== fp32 -> bf16 hi/lo split (Wo only) =====================
__global__ void k_split(const float4* __restrict__ src, ushort4* __restrict__ hi,
                        ushort4* __restrict__ lo) {
    int idx = blockIdx.x * 256 + threadIdx.x;
    float4 x = src[idx];
    ushort4 h, l;
    split1(x.x, h.x, l.x);
    split1(x.y, h.y, l.y);
    split1(x.z, h.z, l.z);
    split1(x.w, h.w, l.w);
    hi[idx] = h;
    lo[idx] = l;
}

// ==================== fused QKV: 256x256 8-phase MFMA GEMM ===================
// T2+T3+T4+T5 template (m201-style): BK=64, 2-deep LDS dbuf, 1 half-tile
// staged per phase via global_load_lds w=16, counted vmcnt(4) gates (never 0
// except final tile), raw s_barrier, setprio around MFMA clusters.
// LDS slot-XOR swizzle: LDS[r][s] holds global 16B-slot s^(r&7); global src
// pre-swizzled (rule 21: inverse-swz SOURCE + swz on READ, linear LDS dest).
// Half-tile issue ledger (h = 4*tile + {A0,A1,B0,B1}), stagger 6:
//   prologue h0..h5; iter lp0..lp7 issue h = 8it+6 .. 8it+13.
//   Slot reads are front-loaded (12+12 ds_read in the tile's first 2 phases),
//   so every stage targets a slot drained before the previous barrier.
#define BAR  __builtin_amdgcn_s_barrier()
#define LGKM0 asm volatile("s_waitcnt lgkmcnt(0)" ::: "memory")
#define VM4  asm volatile("s_waitcnt vmcnt(4)" ::: "memory")
#define VM0  asm volatile("s_waitcnt vmcnt(0)" ::: "memory")
#define PRIO1 __builtin_amdgcn_s_setprio(1)
#define PRIO0 __builtin_amdgcn_s_setprio(0)

#define STA(slot, half, kt) do { \
    const ushort_t* g_ = Xh + sgA + (size_t)((half) * 128) * 2048 + (size_t)(kt) * 64; \
    gl_lds16(g_, &As[slot][((half) * 128 + w * 16) * 64]); \
    gl_lds16(g_ + 8 * 2048, &As[slot][((half) * 128 + w * 16 + 8) * 64]); \
} while (0)

#define STB(slot, half, kt) do { \
    const ushort_t* g_ = Wsel + sgB + (size_t)((half) * 128) * 2048 + (size_t)(kt) * 64; \
    gl_lds16(g_, &Bs[slot][((half) * 128 + w * 16) * 64]); \
    gl_lds16(g_ + 8 * 2048, &Bs[slot][((half) * 128 + w * 16 + 8) * 64]); \
} while (0)

#define RD_A4(DST, slot, MB) \
    _Pragma("unroll") for (int mf = 0; mf < 4; mf++) { \
        DST[mf][0] = *(const bf16x8*)&As[slot][arow + ((MB) + mf) * 1024 + cc0]; \
        DST[mf][1] = *(const bf16x8*)&As[slot][arow + ((MB) + mf) * 1024 + cc1]; \
    }

#define RD_B2(DST, slot, NBB) \
    _Pragma("unroll") for (int nf = 0; nf < 2; nf++) { \
        DST[nf][0] = *(const bf16x8*)&Bs[slot][brow + ((NBB) + nf) * 1024 + cc0]; \
        DST[nf][1] = *(const bf16x8*)&Bs[slot][brow + ((NBB) + nf) * 1024 + cc1]; \
    }

#define PH_MFMA(AF, BF, MB, NBB) do { PRIO1; \
    _Pragma("unroll") for (int mf = 0; mf < 4; mf++) \
    _Pragma("unroll") for (int nf = 0; nf < 2; nf++) { \
        acc[(MB) + mf][(NBB) + nf] = __builtin_amdgcn_mfma_f32_16x16x32_bf16( \
            AF[mf][0], BF[nf][0], acc[(MB) + mf][(NBB) + nf], 0, 0, 0); \
        acc[(MB) + mf][(NBB) + nf] = __builtin_amdgcn_mfma_f32_16x16x32_bf16( \
            AF[mf][1], BF[nf][1], acc[(MB) + mf][(NBB) + nf], 0, 0, 0); \
    } PRIO0; } while (0)

__global__ __launch_bounds__(512, 2)
void k_gemm_qkv8(const ushort_t* __restrict__ Xh,
                 const ushort_t* __restrict__ W0, const ushort_t* __restrict__ W1,
                 const ushort_t* __restrict__ W2,
                 const float* __restrict__ b0, const float* __restrict__ b1,
                 const float* __restrict__ b2,
                 float* __restrict__ o0, float* __restrict__ o1, float* __restrict__ o2) {
    __shared__ ushort_t As[2][256 * 64];
    __shared__ ushort_t Bs[2][256 * 64];
    const int tid = threadIdx.x;
    const int lane = tid & 63;
    const int w = tid >> 6;        // wave 0..7
    const int wm = w >> 2;         // 0..1  (128 output rows each)
    const int wn = w & 3;          // 0..3  (64 output cols each)
    const int quad = lane >> 4;
    const int l15 = lane & 15;

    // bijective XCD swizzle (384 % 8 == 0): each XCD gets 3 contiguous n-panels
    int bid = blockIdx.x;
    bid = (bid & 7) * 48 + (bid >> 3);
    const int bx = bid & 15;       // m-block
    const int by = bid >> 4;       // 0..23
    const int m0 = bx << 8;
    const int mat = by >> 3;
    const int n0 = (by & 7) << 8;
    const ushort_t* Wsel = (mat == 0) ? W0 : (mat == 1) ? W1 : W2;
    const float* bias = (mat == 0) ? b0 : (mat == 1) ? b1 : b2;
    float* out = (mat == 0) ? o0 : (mat == 1) ? o1 : o2;

    // staging addressing: wave w covers rows [w*16, w*16+16) of each half-tile,
    // 2 instrs x (8 rows x 128B). Global col slot pre-swizzled: lcol = (l&7)^(l>>3)
    const int lrow = lane >> 3;
    const int lcol8 = (((lane & 7) ^ lrow) << 3);
    const size_t sgA = (size_t)(m0 + w * 16 + lrow) * 2048 + lcol8;
    const size_t sgB = (size_t)(n0 + w * 16 + lrow) * 2048 + lcol8;

    // fragment-read addressing (swizzled): row R col-slot g -> LDS slot g^(R&7)
    const int arow = (wm * 128 + l15) * 64;
    const int brow = (wn * 64 + l15) * 64;
    const int cc0 = ((quad ^ (l15 & 7)) << 3);
    const int cc1 = cc0 ^ 32;

    f32x4 acc[8][4];
#pragma unroll
    for (int i = 0; i < 8; i++)
#pragma unroll
        for (int j = 0; j < 4; j++) acc[i][j] = (f32x4){0.f, 0.f, 0.f, 0.f};

    // prologue: h0..h5 = tile0 {A0,A1,B0,B1}, tile1 {A0,A1}
    STA(0, 0, 0); STA(0, 1, 0);
    STB(0, 0, 0); STB(0, 1, 0);
    STA(1, 0, 1); STA(1, 1, 1);

    bf16x8 a03[4][2], a47[4][2], b01[2][2], b23[2][2];

    for (int it = 0; it < 16; ++it) {
        const int kt0 = 2 * it, kt1 = 2 * it + 1;
        const bool st = (it < 15);
        // ---- lp0: gate slot0(tile 2it); reads A m0-3 + B n0-1; stage t(2it+1).B0
        VM4; BAR;
        RD_A4(a03, 0, 0); RD_B2(b01, 0, 0);
        STB(1, 0, kt1);                     // h = 8it+6
        BAR; LGKM0;
        PH_MFMA(a03, b01, 0, 0);
        BAR;
        // ---- lp1: reads A m4-7 + B n2-3; stage t(2it+1).B1
        RD_A4(a47, 0, 4); RD_B2(b23, 0, 2);
        STB(1, 1, kt1);                     // h = 8it+7
        BAR; LGKM0;
        PH_MFMA(a03, b23, 0, 2);
        BAR;
        // ---- lp2: stage t(2it+2).A0 (slot0 fully drained at end of lp1)
        if (st) STA(0, 0, kt0 + 2);         // h = 8it+8
        BAR;
        PH_MFMA(a47, b01, 4, 0);
        BAR;
        // ---- lp3: stage t(2it+2).A1
        if (st) STA(0, 1, kt0 + 2);         // h = 8it+9
        BAR;
        PH_MFMA(a47, b23, 4, 2);
        // ---- lp4: gate slot1(tile 2it+1); reads; stage t(2it+2).B0
        if (it == 15) { VM0; } else { VM4; }
        BAR;
        RD_A4(a03, 1, 0); RD_B2(b01, 1, 0);
        if (st) STB(0, 0, kt0 + 2);         // h = 8it+10
        BAR; LGKM0;
        PH_MFMA(a03, b01, 0, 0);
        BAR;
        // ---- lp5
        RD_A4(a47, 1, 4); RD_B2(b23, 1, 2);
        if (st) STB(0, 1, kt0 + 2);         // h = 8it+11
        BAR; LGKM0;
        PH_MFMA(a03, b23, 0, 2);
        BAR;
        // ---- lp6: stage t(2it+3).A0 (slot1 drained at end of lp5)
        if (st) STA(1, 0, kt1 + 2);         // h = 8it+12
        BAR;
        PH_MFMA(a47, b01, 4, 0);
        BAR;
        // ---- lp7: stage t(2it+3).A1
        if (st) STA(1, 1, kt1 + 2);         // h = 8it+13
        BAR;
        PH_MFMA(a47, b23, 4, 2);
        // next iteration's lp0 gate (VM4;BAR) closes this K-tile pair
    }

    // ---- epilogue: bias + store to blocked (B,NH,S,HD) fp32 ----
    float bcolv[4];
#pragma unroll
    for (int nf = 0; nf < 4; nf++) bcolv[nf] = bias[n0 + wn * 64 + nf * 16 + l15];

    const int mbase = m0 + wm * 128 + quad * 4;
#pragma unroll
    for (int mf = 0; mf < 8; mf++)
#pragma unroll
        for (int nf = 0; nf < 4; nf++) {
            const int n = n0 + wn * 64 + nf * 16 + l15;
            const int hh = n >> 7;
            const int d = n & 127;
#pragma unroll
            for (int r = 0; r < 4; r++) {
                const int m = mbase + mf * 16 + r;
                const int bb = m >> 11;
                const int s = m & (SEQ - 1);
                out[((size_t)(bb * NH + hh) * SEQ + s) * HD + d] = acc[mf][nf][r] + bcolv[nf];
            }
        }
}

// ==================== bf16x3 MFMA GEMM (O-projection) ========================
// A (ctx hi/lo) is in BLOCKED layout (B,NH,S,HD): k-offset within a row is
// (kt>>7)*SEQ*HD + (kt&127). B (Wo hi/lo) is row-major K-contiguous.
__global__ __launch_bounds__(256)
void k_gemm_o(const ushort_t* __restrict__ Ah, const ushort_t* __restrict__ Al,
              const ushort_t* __restrict__ Bh, const ushort_t* __restrict__ Bl,
              const float* __restrict__ bias, float* __restrict__ out) {
    __shared__ ushort_t lds[4][128 * 32];
    const int tid = threadIdx.x;
    const int lane = tid & 63;
    const int w = tid >> 6;
    const int wm = w & 1, wn = w >> 1;
    const int quad = lane >> 4;
    const int l15 = lane & 15;
    const int m0 = blockIdx.x << 7;
    const int n0 = blockIdx.y << 7;
    const bool isA = (w < 2);

    const ushort_t* src = (w == 0) ? Ah : (w == 1) ? Al : (w == 2) ? Bh : Bl;
    const int lrow = lane >> 2;
    const int lk = (lane & 3) << 3;
    const ushort_t* gp[8];
    ushort_t* lp[8];
#pragma unroll
    for (int i = 0; i < 8; i++) {
        if (isA) {
            int m = m0 + i * 16 + lrow;
            int bb = m >> 11, s = m & (SEQ - 1);
            gp[i] = src + ((size_t)bb * NH * SEQ + s) * HD + lk;
        } else {
            gp[i] = src + (size_t)(n0 + i * 16 + lrow) * K_DIM + lk;
        }
        lp[i] = &lds[w][i * 512];
    }

    f32x4 acc[4][4];
#pragma unroll
    for (int i = 0; i < 4; i++)
#pragma unroll
        for (int j = 0; j < 4; j++) acc[i][j] = (f32x4){0.f, 0.f, 0.f, 0.f};

    const int aoff = (wm * 64 + l15) * 32 + quad * 8;
    const int boff = (wn * 64 + l15) * 32 + quad * 8;

#pragma unroll
    for (int i = 0; i < 8; i++) gl_lds16(gp[i], lp[i]);
    __syncthreads();
    bf16x8 ah[4], al[4], bh[4], bl[4];
#pragma unroll
    for (int f = 0; f < 4; f++) {
        ah[f] = *(const bf16x8*)&lds[0][aoff + f * 512];
        al[f] = *(const bf16x8*)&lds[1][aoff + f * 512];
        bh[f] = *(const bf16x8*)&lds[2][boff + f * 512];
        bl[f] = *(const bf16x8*)&lds[3][boff + f * 512];
    }

    for (int kt = 32; kt <= K_DIM; kt += 32) {
        __syncthreads();
        if (kt < K_DIM) {
            const size_t koff = isA ? ((size_t)(kt >> 7) * (SEQ * HD) + (kt & 127)) : (size_t)kt;
#pragma unroll
            for (int i = 0; i < 8; i++) gl_lds16(gp[i] + koff, lp[i]);
        }
#pragma unroll
        for (int fm = 0; fm < 4; fm++)
#pragma unroll
            for (int fn = 0; fn < 4; fn++) {
                acc[fm][fn] = __builtin_amdgcn_mfma_f32_16x16x32_bf16(ah[fm], bh[fn], acc[fm][fn], 0, 0, 0);
                acc[fm][fn] = __builtin_amdgcn_mfma_f32_16x16x32_bf16(ah[fm], bl[fn], acc[fm][fn], 0, 0, 0);
                acc[fm][fn] = __builtin_amdgcn_mfma_f32_16x16x32_bf16(al[fm], bh[fn], acc[fm][fn], 0, 0, 0);
            }
        if (kt < K_DIM) {
            __syncthreads();
#pragma unroll
            for (int f = 0; f < 4; f++) {
                ah[f] = *(const bf16x8*)&lds[0][aoff + f * 512];
                al[f] = *(const bf16x8*)&lds[1][aoff + f * 512];
                bh[f] = *(const bf16x8*)&lds[2][boff + f * 512];
                bl[f] = *(const bf16x8*)&lds[3][boff + f * 512];
            }
        }
    }

    float bcolv[4];
#pragma unroll
    for (int fn = 0; fn < 4; fn++) bcolv[fn] = bias[n0 + wn * 64 + fn * 16 + l15];

    const int mb = m0 + wm * 64 + quad * 4;
    const int nb = n0 + wn * 64 + l15;
#pragma unroll
    for (int fm = 0; fm < 4; fm++)
#pragma unroll
        for (int fn = 0; fn < 4; fn++)
#pragma unroll
            for (int r = 0; r < 4; r++)
                out[(size_t)(mb + fm * 16 + r) * HIDDEN + nb + fn * 16] =
                    acc[fm][fn][r] + bcolv[fn];
}

// ==================== RoPE + pack to bf16 (Q scaled by 1/sqrt(HD)) ===========
__global__ void k_rope_pack(const float* __restrict__ q, const float* __restrict__ k,
                            const float* __restrict__ ct, const float* __restrict__ st,
                            ushort_t* __restrict__ Qb, ushort_t* __restrict__ Kb) {
    int idx = blockIdx.x * 256 + threadIdx.x;   // exactly NB*NH*SEQ*64 threads
    int d = idx & 63;
    int s = (idx >> 6) & (SEQ - 1);
    int bh = idx >> 17;
    size_t base = ((size_t)bh * SEQ + s) * HD;
    float c = ct[(s << 6) + d], sn = st[(s << 6) + d];
    const float scq = 0.08838834764831845f;
    float q0 = q[base + d], q1 = q[base + d + 64];
    Qb[base + d]      = bf16r((q0 * c - q1 * sn) * scq);
    Qb[base + d + 64] = bf16r((q1 * c + q0 * sn) * scq);
    float k0 = k[base + d], k1 = k[base + d + 64];
    Kb[base + d]      = bf16r(k0 * c - k1 * sn);
    Kb[base + d + 64] = bf16r(k1 * c + k0 * sn);
}

// ==================== V transpose + pack: (B,H,S,D) fp32 -> (B,H,D,S) bf16 ===
__global__ __launch_bounds__(256)
void k_vpack(const float* __restrict__ v, ushort_t* __restrict__ vt) {
    __shared__ float t[64][65];
    const int tid = threadIdx.x;
    const int bh = blockIdx.z;
    const int s0 = blockIdx.x << 6;
    const int d0 = blockIdx.y << 6;
    const float* src = v + ((size_t)bh * SEQ + s0) * HD + d0;
    const int rr = tid >> 4;
    const int cc = (tid & 15) << 2;
#pragma unroll
    for (int i = 0; i < 4; i++) {
        float4 x = *(const float4*)(src + (size_t)(i * 16 + rr) * HD + cc);
        t[i * 16 + rr][cc] = x.x;
        t[i * 16 + rr][cc + 1] = x.y;
        t[i * 16 + rr][cc + 2] = x.z;
        t[i * 16 + rr][cc + 3] = x.w;
    }
    __syncthreads();
    const int dr = tid >> 2;
    const int sc_ = (tid & 3) << 4;
    ushort_t* dst = vt + ((size_t)bh * HD + d0 + dr) * SEQ + s0 + sc_;
    u16x8 o0, o1;
#pragma unroll
    for (int u = 0; u < 8; u++) o0[u] = bf16r(t[sc_ + u][dr]);
#pragma unroll
    for (int u = 0; u < 8; u++) o1[u] = bf16r(t[sc_ + 8 + u][dr]);
    *(u16x8*)dst = o0;
    *(u16x8*)(dst + 8) = o1;
}

// ==================== MFMA flash attention v4 ================================
// R4 loop structure (128 q-rows/block, 4 waves x 32 rows, VGPR<=128, 2 blk/CU)
// + R5's verified wins: XCD swizzle (bh = idx&31 -> all 16 q-tiles of a head
// land on one XCD; K/V stay L2-resident: FETCH 183->40MB) and coalesced
// epilogue via LDS re-layout into BLOCKED (B,NH,S,HD) ctx (kills the 8x
// partial-line write amplification: WRITE 258->~40MB).
__global__ __launch_bounds__(256, 2)
void k_flash_mfma(const ushort_t* __restrict__ Qb, const ushort_t* __restrict__ Kb,
                  const ushort_t* __restrict__ Vt,
                  ushort_t* __restrict__ ch, ushort_t* __restrict__ cl) {
    __shared__ ushort_t KV[128 * 136];
    __shared__ ushort_t Ps[128 * 136];
    const int tid = threadIdx.x;
    const int lane = tid & 63;
    const int w = tid >> 6;
    const int quad = lane >> 4;
    const int l15 = lane & 15;
    const int bi = blockIdx.x;
    const int bh = bi & 31;              // XCD swizzle: bh%8 == XCD id
    const int qt = bi >> 5;              // 0..15 (128 q rows each)
    const ushort_t* Qg = Qb + ((size_t)bh * SEQ + ((size_t)qt << 7)) * HD;
    const ushort_t* Kg = Kb + (size_t)bh * SEQ * HD;
    const ushort_t* Vg = Vt + (size_t)bh * HD * SEQ;

    // persistent Q fragments (B-operand): rows w*32+qi*16+l15, k = ks*32+quad*8
    bf16x8 qf[2][4];
#pragma unroll
    for (int qi = 0; qi < 2; qi++)
#pragma unroll
        for (int ks = 0; ks < 4; ks++)
            qf[qi][ks] = *(const bf16x8*)(Qg + (size_t)(w * 32 + qi * 16 + l15) * HD + ks * 32 + quad * 8);

    const int sr = tid >> 4;            // staging row 0..15
    const int sc8 = (tid & 15) << 3;    // staging col (8 elems = 16B)

    // prefetch chunk 0 K and V^T into registers
    u16x8 Kreg[8], Vreg[8];
#pragma unroll
    for (int i = 0; i < 8; i++)
        Kreg[i] = *(const u16x8*)(Kg + (size_t)(i * 16 + sr) * HD + sc8);
#pragma unroll
    for (int i = 0; i < 8; i++)
        Vreg[i] = *(const u16x8*)(Vg + (size_t)(i * 16 + sr) * SEQ + sc8);

    f32x4 acc[2][8];
#pragma unroll
    for (int qi = 0; qi < 2; qi++)
#pragma unroll
        for (int d = 0; d < 8; d++) acc[qi][d] = (f32x4){0.f, 0.f, 0.f, 0.f};
    float lp[2] = {0.f, 0.f};

    for (int kt = 0; kt < SEQ; kt += 128) {
        const int np = kt + 128;
        __syncthreads();                // prev PV reads of KV done
#pragma unroll
        for (int i = 0; i < 8; i++)     // stage K_i; refill Kreg = K_{i+1}
            *(u16x8*)&KV[(i * 16 + sr) * 136 + sc8] = Kreg[i];
        if (np < SEQ) {
#pragma unroll
            for (int i = 0; i < 8; i++)
                Kreg[i] = *(const u16x8*)(Kg + (size_t)(np + i * 16 + sr) * HD + sc8);
        }
        __syncthreads();

        // ---- scores transposed: sc[qi][j] = K(16 rows) x Q(16 rows)^T ----
        f32x4 sc[2][8];
#pragma unroll
        for (int qi = 0; qi < 2; qi++)
#pragma unroll
            for (int j = 0; j < 8; j++) sc[qi][j] = (f32x4){0.f, 0.f, 0.f, 0.f};
#pragma unroll
        for (int ks = 0; ks < 4; ks++) {
#pragma unroll
            for (int jh = 0; jh < 2; jh++) {
                bf16x8 kf[4];
#pragma unroll
                for (int j = 0; j < 4; j++)
                    kf[j] = *(const bf16x8*)&KV[((jh * 4 + j) * 16 + l15) * 136 + ks * 32 + quad * 8];
#pragma unroll
                for (int qi = 0; qi < 2; qi++)
#pragma unroll
                    for (int j = 0; j < 4; j++)
                        sc[qi][jh * 4 + j] = __builtin_amdgcn_mfma_f32_16x16x32_bf16(
                            kf[j], qf[qi][ks], sc[qi][jh * 4 + j], 0, 0, 0);
            }
        }

        // ---- p = exp(score); accumulate l; write P (8B contiguous) ----
#pragma unroll
        for (int qi = 0; qi < 2; qi++) {
            const int prow = (w * 32 + qi * 16 + l15) * 136 + quad * 4;
#pragma unroll
            for (int j = 0; j < 8; j++) {
                float p0 = __expf(sc[qi][j][0]);
                float p1 = __expf(sc[qi][j][1]);
                float p2 = __expf(sc[qi][j][2]);
                float p3 = __expf(sc[qi][j][3]);
                lp[qi] += (p0 + p1) + (p2 + p3);
                __hip_bfloat162 lo2 = __float22bfloat162_rn({p0, p1});
                __hip_bfloat162 hi2 = __float22bfloat162_rn({p2, p3});
                uint2 pk = make_uint2(*(u32*)&lo2, *(u32*)&hi2);
                *(uint2*)&Ps[prow + j * 16] = pk;
            }
        }
        __syncthreads();                // kf reads done + Ps visible
#pragma unroll
        for (int i = 0; i < 8; i++)     // stage V_i; refill Vreg = V_{i+1}
            *(u16x8*)&KV[(i * 16 + sr) * 136 + sc8] = Vreg[i];
        if (np < SEQ) {
#pragma unroll
            for (int i = 0; i < 8; i++)
                Vreg[i] = *(const u16x8*)(Vg + (size_t)(i * 16 + sr) * SEQ + np + sc8);
        }
        __syncthreads();

        // ---- PV transposed: acc[qi][db] = V^T(16 d-rows) x P^T ----
#pragma unroll
        for (int ks = 0; ks < 4; ks++) {
            bf16x8 pf[2];
#pragma unroll
            for (int qi = 0; qi < 2; qi++)
                pf[qi] = *(const bf16x8*)&Ps[(w * 32 + qi * 16 + l15) * 136 + ks * 32 + quad * 8];
#pragma unroll
            for (int db = 0; db < 8; db++) {
                bf16x8 vf = *(const bf16x8*)&KV[(db * 16 + l15) * 136 + ks * 32 + quad * 8];
#pragma unroll
                for (int qi = 0; qi < 2; qi++)
                    acc[qi][db] = __builtin_amdgcn_mfma_f32_16x16x32_bf16(vf, pf[qi], acc[qi][db], 0, 0, 0);
            }
        }
    }

    // ---- epilogue: l-reduce, normalize, re-layout via Ps, coalesced store ----
    float inv[2];
#pragma unroll
    for (int qi = 0; qi < 2; qi++) {
        float l = lp[qi];
        l += __shfl_xor(l, 16);
        l += __shfl_xor(l, 32);
        inv[qi] = 1.0f / l;
    }
    const size_t obase = ((size_t)bh * SEQ + ((size_t)qt << 7)) * HD;

    __syncthreads();                    // final PV pf reads of Ps done
    // hi pass
#pragma unroll
    for (int qi = 0; qi < 2; qi++)
#pragma unroll
        for (int db = 0; db < 8; db++) {
            ushort4 hh;
            ushort_t dum;
            split1(acc[qi][db][0] * inv[qi], hh.x, dum);
            split1(acc[qi][db][1] * inv[qi], hh.y, dum);
            split1(acc[qi][db][2] * inv[qi], hh.z, dum);
            split1(acc[qi][db][3] * inv[qi], hh.w, dum);
            *(ushort4*)&Ps[(w * 32 + qi * 16 + l15) * 136 + db * 16 + quad * 4] = hh;
        }
    __syncthreads();
#pragma unroll
    for (int t = 0; t < 8; t++) {
        int c = t * 256 + tid;
        int row = c >> 4, col8 = (c & 15) << 3;
        *(u16x8*)&ch[obase + (size_t)row * HD + col8] = *(const u16x8*)&Ps[row * 136 + col8];
    }
    __syncthreads();
    // lo pass
#pragma unroll
    for (int qi = 0; qi < 2; qi++)
#pragma unroll
        for (int db = 0; db < 8; db++) {
            ushort4 ll;
            ushort_t dum;
            split1(acc[qi][db][0] * inv[qi], dum, ll.x);
            split1(acc[qi][db][1] * inv[qi], dum, ll.y);
            split1(acc[qi][db][2] * inv[qi], dum, ll.z);
            split1(acc[qi][db][3] * inv[qi], dum, ll.w);
            *(ushort4*)&Ps[(w * 32 + qi * 16 + l15) * 136 + db * 16 + quad * 4] = ll;
        }
    __syncthreads();
#pragma unroll
    for (int t = 0; t < 8; t++) {
        int c = t * 256 + tid;
        int row = c >> 4, col8 = (c & 15) << 3;
        *(u16x8*)&cl[obase + (size_t)row * HD + col8] = *(const u16x8*)&Ps[row * 136 + col8];
    }
}

// ==================== launch =================================================
extern "C" void kernel_launch(void* const* d_in, const int* in_sizes, int n_in,
                              void* d_out, int out_size, void* d_ws, size_t ws_size,
                              hipStream_t stream) {
    const float* X  = (const float*)d_in[0];
    const float* Wq = (const float*)d_in[1];
    const float* bq = (const float*)d_in[2];
    const float* Wk = (const float*)d_in[3];
    const float* bk = (const float*)d_in[4];
    const float* Wv = (const float*)d_in[5];
    const float* bv = (const float*)d_in[6];
    const float* Wo = (const float*)d_in[7];
    const float* bo = (const float*)d_in[8];
    float* out = (float*)d_out;

    const size_t QS = (size_t)NB * NH * SEQ * HD;   // 8,388,608 elems
    const size_t WS = (size_t)HIDDEN * HIDDEN;      // 4,194,304 elems
    float* q_ws = (float*)d_ws;
    float* k_ws = q_ws + QS;
    float* v_ws = k_ws + QS;
    float* cost = v_ws + QS;
    float* sint = cost + (size_t)SEQ * 64;
    ushort_t* Xh = (ushort_t*)(sint + (size_t)SEQ * 64);  // -> Qb after QKV
    ushort_t* Wh0 = Xh + QS;
    ushort_t* Wh1 = Wh0 + WS;
    ushort_t* Wh2 = Wh1 + WS;
    ushort_t* Woh = Wh2 + WS;
    ushort_t* Wol = Woh + WS;
    ushort_t* Kb  = Wol + WS;
    ushort_t* Vtb = Kb + QS;
    ushort_t* ctxh = (ushort_t*)q_ws;                     // blocked ctx over dead q_ws
    ushort_t* ctxl = ctxh + QS;

    k_rope_tables<<<(SEQ * 64) / 256, 256, 0, stream>>>(cost, sint);

    k_cvt_all<<<(XG + 3 * WG) / 256, 256, 0, stream>>>(
        (const float4*)X, (const float4*)Wq, (const float4*)Wk, (const float4*)Wv,
        (ushort4*)Xh, (ushort4*)Wh0, (ushort4*)Wh1, (ushort4*)Wh2);
    k_split<<<WS / 4 / 256, 256, 0, stream>>>((const float4*)Wo, (ushort4*)Woh, (ushort4*)Wol);

    k_gemm_qkv8<<<384, 512, 0, stream>>>(Xh, Wh0, Wh1, Wh2, bq, bk, bv,
                                         q_ws, k_ws, v_ws);

    ushort_t* Qbb = Xh;   // X bf16 dead after QKV GEMM
    k_rope_pack<<<(NB * NH * SEQ * 64) / 256, 256, 0, stream>>>(q_ws, k_ws, cost, sint, Qbb, Kb);
    k_vpack<<<dim3(SEQ / 64, HD / 64, NB * NH), 256, 0, stream>>>(v_ws, Vtb);

    k_flash_mfma<<<512, 256, 0, stream>>>(Qbb, Kb, Vtb, ctxh, ctxl);

    k_gemm_o<<<dim3(32, 16), 256, 0, stream>>>(ctxh, ctxl, Woh, Wol, bo, out);
}

// Round 2
// 495.427 us; speedup vs baseline: 1.0182x; 1.0182x over previous
//
#include <hip/hip_runtime.h>
#include <hip/hip_bf16.h>
#include <math.h>

#define HIDDEN 2048
#define NH 16
#define HD 128
#define NB 2
#define SEQ 2048
#define K_DIM 2048

typedef unsigned int u32;
typedef unsigned short ushort_t;
typedef __bf16 bf16x8 __attribute__((ext_vector_type(8)));
typedef float f32x4 __attribute__((ext_vector_type(4)));
typedef ushort_t u16x8 __attribute__((ext_vector_type(8)));

// ---------- fp32 -> (bf16 hi, bf16 lo) split, RNE both halves ----------
__device__ __forceinline__ void split1(float x, unsigned short& h, unsigned short& l) {
    u32 u = __float_as_uint(x);
    u32 hr = (u + 0x7FFFu + ((u >> 16) & 1u)) >> 16;
    h = (unsigned short)hr;
    float r = x - __uint_as_float(hr << 16);
    u32 u2 = __float_as_uint(r);
    l = (unsigned short)((u2 + 0x7FFFu + ((u2 >> 16) & 1u)) >> 16);
}

__device__ __forceinline__ ushort_t bf16r(float x) {
    u32 u = __float_as_uint(x);
    return (ushort_t)((u + 0x7FFFu + ((u >> 16) & 1u)) >> 16);
}

__device__ __forceinline__ void gl_lds16(const void* g, void* l) {
    __builtin_amdgcn_global_load_lds(
        (const __attribute__((address_space(1))) u32*)g,
        (__attribute__((address_space(3))) u32*)l, 16, 0, 0);
}

// ==================== RoPE tables (double-precision trig) ====================
__global__ void k_rope_tables(float* __restrict__ ct, float* __restrict__ st) {
    int idx = blockIdx.x * 256 + threadIdx.x;   // exactly SEQ*64 threads
    int s = idx >> 6, d = idx & 63;
    double inv = pow(10000.0, -(double)d * (1.0 / 64.0));
    double ang = (double)s * inv;
    ct[idx] = (float)cos(ang);
    st[idx] = (float)sin(ang);
}

// ==================== fused fp32 -> bf16 (hi only) for X, Wq, Wk, Wv ========
#define XG 2097152   // X float4 groups
#define WG 1048576   // W float4 groups
__global__ void k_cvt_all(const float4* __restrict__ X, const float4* __restrict__ W0,
                          const float4* __restrict__ W1, const float4* __restrict__ W2,
                          ushort4* __restrict__ Xh, ushort4* __restrict__ H0,
                          ushort4* __restrict__ H1, ushort4* __restrict__ H2) {
    int idx = blockIdx.x * 256 + threadIdx.x;   // XG + 3*WG threads
    const float4* src;
    ushort4* dst;
    int off;
    if (idx < XG) { src = X; dst = Xh; off = idx; }
    else {
        int t = idx - XG;
        int m = t >> 20;        // WG = 2^20
        off = t & (WG - 1);
        src = (m == 0) ? W0 : (m == 1) ? W1 : W2;
        dst = (m == 0) ? H0 : (m == 1) ? H1 : H2;
    }
    float4 x = src[off];
    ushort4 h;
    h.x = bf16r(x.x); h.y = bf16r(x.y); h.z = bf16r(x.z); h.w = bf16r(x.w);
    dst[off] = h;
}

// ==================== fp32 -> bf16 hi/lo split (Wo only) =====================
__global__ void k_split(const float4* __restrict__ src, ushort4* __restrict__ hi,
                        ushort4* __restrict__ lo) {
    int idx = blockIdx.x * 256 + threadIdx.x;
    float4 x = src[idx];
    ushort4 h, l;
    split1(x.x, h.x, l.x);
    split1(x.y, h.y, l.y);
    split1(x.z, h.z, l.z);
    split1(x.w, h.w, l.w);
    hi[idx] = h;
    lo[idx] = l;
}

// ==================== fused QKV: 256x256 relaxed-pipeline MFMA GEMM ==========
// R2: drop the 8-phase lockstep. Per K-tile (BK=64): stage next tile (8
// global_load_lds), counted-vmcnt gate (VM8, never 0 mid-loop), barrier,
// issue all 24 fragment ds_read_b128, then 64 MFMAs with NO explicit
// lgkmcnt -- the compiler inserts fine-grained counted lgkmcnt so the MFMA
// cluster overlaps the read tail (m97 asm evidence). 2 barriers per K-tile.
// Race audit: end-of-tile barrier is reached only after each wave's last
// MFMA, whose operands require all that wave's 24 reads complete => slot
// fully drained before the next phase's stage writes to it. The VM8 gate
// (8 loads = exactly next tile in flight) + barrier certifies current-tile
// LDS data before any read.
// T2 LDS slot-XOR swizzle kept (conflicts measured 0): LDS[r][slot s] holds
// global 16B-slot s^(r&7); source pre-swizzled, read swizzled, dest linear.
#define BAR  __builtin_amdgcn_s_barrier()
#define VM8  asm volatile("s_waitcnt vmcnt(8)" ::: "memory")
#define VM0  asm volatile("s_waitcnt vmcnt(0)" ::: "memory")
#define PRIO1 __builtin_amdgcn_s_setprio(1)
#define PRIO0 __builtin_amdgcn_s_setprio(0)

#define STA(slot, half, kt) do { \
    const ushort_t* g_ = Xh + sgA + (size_t)((half) * 128) * 2048 + (size_t)(kt) * 64; \
    gl_lds16(g_, &As[slot][((half) * 128 + w * 16) * 64]); \
    gl_lds16(g_ + 8 * 2048, &As[slot][((half) * 128 + w * 16 + 8) * 64]); \
} while (0)

#define STB(slot, half, kt) do { \
    const ushort_t* g_ = Wsel + sgB + (size_t)((half) * 128) * 2048 + (size_t)(kt) * 64; \
    gl_lds16(g_, &Bs[slot][((half) * 128 + w * 16) * 64]); \
    gl_lds16(g_ + 8 * 2048, &Bs[slot][((half) * 128 + w * 16 + 8) * 64]); \
} while (0)

#define STAGE_T(slot, kt) do { \
    STA(slot, 0, kt); STA(slot, 1, kt); STB(slot, 0, kt); STB(slot, 1, kt); \
} while (0)

#define RD_A4(DST, slot, MB) \
    _Pragma("unroll") for (int mf = 0; mf < 4; mf++) { \
        DST[mf][0] = *(const bf16x8*)&As[slot][arow + ((MB) + mf) * 1024 + cc0]; \
        DST[mf][1] = *(const bf16x8*)&As[slot][arow + ((MB) + mf) * 1024 + cc1]; \
    }

#define RD_B2(DST, slot, NBB) \
    _Pragma("unroll") for (int nf = 0; nf < 2; nf++) { \
        DST[nf][0] = *(const bf16x8*)&Bs[slot][brow + ((NBB) + nf) * 1024 + cc0]; \
        DST[nf][1] = *(const bf16x8*)&Bs[slot][brow + ((NBB) + nf) * 1024 + cc1]; \
    }

#define PH_MFMA(AF, BF, MB, NBB) do { PRIO1; \
    _Pragma("unroll") for (int mf = 0; mf < 4; mf++) \
    _Pragma("unroll") for (int nf = 0; nf < 2; nf++) { \
        acc[(MB) + mf][(NBB) + nf] = __builtin_amdgcn_mfma_f32_16x16x32_bf16( \
            AF[mf][0], BF[nf][0], acc[(MB) + mf][(NBB) + nf], 0, 0, 0); \
        acc[(MB) + mf][(NBB) + nf] = __builtin_amdgcn_mfma_f32_16x16x32_bf16( \
            AF[mf][1], BF[nf][1], acc[(MB) + mf][(NBB) + nf], 0, 0, 0); \
    } PRIO0; } while (0)

// one full K-tile: reads issued up front (order = a03,b01,a47,b23), MFMA
// batches ordered to consume in read order so compiler-counted lgkmcnt
// overlaps the tail.
#define KTILE(slot) do { \
    RD_A4(a03, slot, 0); RD_B2(b01, slot, 0); \
    RD_A4(a47, slot, 4); RD_B2(b23, slot, 2); \
    PH_MFMA(a03, b01, 0, 0); \
    PH_MFMA(a47, b01, 4, 0); \
    PH_MFMA(a03, b23, 0, 2); \
    PH_MFMA(a47, b23, 4, 2); \
} while (0)

__global__ __launch_bounds__(512, 2)
void k_gemm_qkv8(const ushort_t* __restrict__ Xh,
                 const ushort_t* __restrict__ W0, const ushort_t* __restrict__ W1,
                 const ushort_t* __restrict__ W2,
                 const float* __restrict__ b0, const float* __restrict__ b1,
                 const float* __restrict__ b2,
                 float* __restrict__ o0, float* __restrict__ o1, float* __restrict__ o2) {
    __shared__ ushort_t As[2][256 * 64];
    __shared__ ushort_t Bs[2][256 * 64];
    const int tid = threadIdx.x;
    const int lane = tid & 63;
    const int w = tid >> 6;        // wave 0..7
    const int wm = w >> 2;         // 0..1  (128 output rows each)
    const int wn = w & 3;          // 0..3  (64 output cols each)
    const int quad = lane >> 4;
    const int l15 = lane & 15;

    // bijective XCD swizzle (384 % 8 == 0): each XCD gets 3 contiguous n-panels
    int bid = blockIdx.x;
    bid = (bid & 7) * 48 + (bid >> 3);
    const int bx = bid & 15;       // m-block
    const int by = bid >> 4;       // 0..23
    const int m0 = bx << 8;
    const int mat = by >> 3;
    const int n0 = (by & 7) << 8;
    const ushort_t* Wsel = (mat == 0) ? W0 : (mat == 1) ? W1 : W2;
    const float* bias = (mat == 0) ? b0 : (mat == 1) ? b1 : b2;
    float* out = (mat == 0) ? o0 : (mat == 1) ? o1 : o2;

    // staging addressing: wave w covers rows [w*16, w*16+16) of each half-tile,
    // 2 instrs x (8 rows x 128B). Global col slot pre-swizzled: lcol = (l&7)^(l>>3)
    const int lrow = lane >> 3;
    const int lcol8 = (((lane & 7) ^ lrow) << 3);
    const size_t sgA = (size_t)(m0 + w * 16 + lrow) * 2048 + lcol8;
    const size_t sgB = (size_t)(n0 + w * 16 + lrow) * 2048 + lcol8;

    // fragment-read addressing (swizzled): row R col-slot g -> LDS slot g^(R&7)
    const int arow = (wm * 128 + l15) * 64;
    const int brow = (wn * 64 + l15) * 64;
    const int cc0 = ((quad ^ (l15 & 7)) << 3);
    const int cc1 = cc0 ^ 32;

    f32x4 acc[8][4];
#pragma unroll
    for (int i = 0; i < 8; i++)
#pragma unroll
        for (int j = 0; j < 4; j++) acc[i][j] = (f32x4){0.f, 0.f, 0.f, 0.f};

    bf16x8 a03[4][2], a47[4][2], b01[2][2], b23[2][2];

    // prologue: tile0 -> slot0 (8 loads)
    STAGE_T(0, 0);

    for (int it = 0; it < 16; ++it) {
        // ---- K-tile 2it (slot0); stage tile 2it+1 -> slot1 (slot1 reads
        //      finished at prev tile's end barrier)
        STAGE_T(1, 2 * it + 1);
        VM8;                        // tile 2it (oldest 8 loads) complete
        BAR;                        // ...for ALL waves
        KTILE(0);
        BAR;                        // all waves' slot0 reads done -> slot0 reusable
        // ---- K-tile 2it+1 (slot1); stage tile 2it+2 -> slot0
        if (it < 15) { STAGE_T(0, 2 * it + 2); VM8; } else { VM0; }
        BAR;
        KTILE(1);
        BAR;
    }

    // ---- epilogue: bias + store to blocked (B,NH,S,HD) fp32 ----
    float bcolv[4];
#pragma unroll
    for (int nf = 0; nf < 4; nf++) bcolv[nf] = bias[n0 + wn * 64 + nf * 16 + l15];

    const int mbase = m0 + wm * 128 + quad * 4;
#pragma unroll
    for (int mf = 0; mf < 8; mf++)
#pragma unroll
        for (int nf = 0; nf < 4; nf++) {
            const int n = n0 + wn * 64 + nf * 16 + l15;
            const int hh = n >> 7;
            const int d = n & 127;
#pragma unroll
            for (int r = 0; r < 4; r++) {
                const int m = mbase + mf * 16 + r;
                const int bb = m >> 11;
                const int s = m & (SEQ - 1);
                out[((size_t)(bb * NH + hh) * SEQ + s) * HD + d] = acc[mf][nf][r] + bcolv[nf];
            }
        }
}

// ==================== bf16x3 MFMA GEMM (O-projection) ========================
// A (ctx hi/lo) is in BLOCKED layout (B,NH,S,HD): k-offset within a row is
// (kt>>7)*SEQ*HD + (kt&127). B (Wo hi/lo) is row-major K-contiguous.
__global__ __launch_bounds__(256)
void k_gemm_o(const ushort_t* __restrict__ Ah, const ushort_t* __restrict__ Al,
              const ushort_t* __restrict__ Bh, const ushort_t* __restrict__ Bl,
              const float* __restrict__ bias, float* __restrict__ out) {
    __shared__ ushort_t lds[4][128 * 32];
    const int tid = threadIdx.x;
    const int lane = tid & 63;
    const int w = tid >> 6;
    const int wm = w & 1, wn = w >> 1;
    const int quad = lane >> 4;
    const int l15 = lane & 15;
    const int m0 = blockIdx.x << 7;
    const int n0 = blockIdx.y << 7;
    const bool isA = (w < 2);

    const ushort_t* src = (w == 0) ? Ah : (w == 1) ? Al : (w == 2) ? Bh : Bl;
    const int lrow = lane >> 2;
    const int lk = (lane & 3) << 3;
    const ushort_t* gp[8];
    ushort_t* lp[8];
#pragma unroll
    for (int i = 0; i < 8; i++) {
        if (isA) {
            int m = m0 + i * 16 + lrow;
            int bb = m >> 11, s = m & (SEQ - 1);
            gp[i] = src + ((size_t)bb * NH * SEQ + s) * HD + lk;
        } else {
            gp[i] = src + (size_t)(n0 + i * 16 + lrow) * K_DIM + lk;
        }
        lp[i] = &lds[w][i * 512];
    }

    f32x4 acc[4][4];
#pragma unroll
    for (int i = 0; i < 4; i++)
#pragma unroll
        for (int j = 0; j < 4; j++) acc[i][j] = (f32x4){0.f, 0.f, 0.f, 0.f};

    const int aoff = (wm * 64 + l15) * 32 + quad * 8;
    const int boff = (wn * 64 + l15) * 32 + quad * 8;

#pragma unroll
    for (int i = 0; i < 8; i++) gl_lds16(gp[i], lp[i]);
    __syncthreads();
    bf16x8 ah[4], al[4], bh[4], bl[4];
#pragma unroll
    for (int f = 0; f < 4; f++) {
        ah[f] = *(const bf16x8*)&lds[0][aoff + f * 512];
        al[f] = *(const bf16x8*)&lds[1][aoff + f * 512];
        bh[f] = *(const bf16x8*)&lds[2][boff + f * 512];
        bl[f] = *(const bf16x8*)&lds[3][boff + f * 512];
    }

    for (int kt = 32; kt <= K_DIM; kt += 32) {
        __syncthreads();
        if (kt < K_DIM) {
            const size_t koff = isA ? ((size_t)(kt >> 7) * (SEQ * HD) + (kt & 127)) : (size_t)kt;
#pragma unroll
            for (int i = 0; i < 8; i++) gl_lds16(gp[i] + koff, lp[i]);
        }
#pragma unroll
        for (int fm = 0; fm < 4; fm++)
#pragma unroll
            for (int fn = 0; fn < 4; fn++) {
                acc[fm][fn] = __builtin_amdgcn_mfma_f32_16x16x32_bf16(ah[fm], bh[fn], acc[fm][fn], 0, 0, 0);
                acc[fm][fn] = __builtin_amdgcn_mfma_f32_16x16x32_bf16(ah[fm], bl[fn], acc[fm][fn], 0, 0, 0);
                acc[fm][fn] = __builtin_amdgcn_mfma_f32_16x16x32_bf16(al[fm], bh[fn], acc[fm][fn], 0, 0, 0);
            }
        if (kt < K_DIM) {
            __syncthreads();
#pragma unroll
            for (int f = 0; f < 4; f++) {
                ah[f] = *(const bf16x8*)&lds[0][aoff + f * 512];
                al[f] = *(const bf16x8*)&lds[1][aoff + f * 512];
                bh[f] = *(const bf16x8*)&lds[2][boff + f * 512];
                bl[f] = *(const bf16x8*)&lds[3][boff + f * 512];
            }
        }
    }

    float bcolv[4];
#pragma unroll
    for (int fn = 0; fn < 4; fn++) bcolv[fn] = bias[n0 + wn * 64 + fn * 16 + l15];

    const int mb = m0 + wm * 64 + quad * 4;
    const int nb = n0 + wn * 64 + l15;
#pragma unroll
    for (int fm = 0; fm < 4; fm++)
#pragma unroll
        for (int fn = 0; fn < 4; fn++)
#pragma unroll
            for (int r = 0; r < 4; r++)
                out[(size_t)(mb + fm * 16 + r) * HIDDEN + nb + fn * 16] =
                    acc[fm][fn][r] + bcolv[fn];
}

// ==================== RoPE + pack to bf16 (Q scaled by 1/sqrt(HD)) ===========
__global__ void k_rope_pack(const float* __restrict__ q, const float* __restrict__ k,
                            const float* __restrict__ ct, const float* __restrict__ st,
                            ushort_t* __restrict__ Qb, ushort_t* __restrict__ Kb) {
    int idx = blockIdx.x * 256 + threadIdx.x;   // exactly NB*NH*SEQ*64 threads
    int d = idx & 63;
    int s = (idx >> 6) & (SEQ - 1);
    int bh = idx >> 17;
    size_t base = ((size_t)bh * SEQ + s) * HD;
    float c = ct[(s << 6) + d], sn = st[(s << 6) + d];
    const float scq = 0.08838834764831845f;
    float q0 = q[base + d], q1 = q[base + d + 64];
    Qb[base + d]      = bf16r((q0 * c - q1 * sn) * scq);
    Qb[base + d + 64] = bf16r((q1 * c + q0 * sn) * scq);
    float k0 = k[base + d], k1 = k[base + d + 64];
    Kb[base + d]      = bf16r(k0 * c - k1 * sn);
    Kb[base + d + 64] = bf16r(k1 * c + k0 * sn);
}

// ==================== V transpose + pack: (B,H,S,D) fp32 -> (B,H,D,S) bf16 ===
__global__ __launch_bounds__(256)
void k_vpack(const float* __restrict__ v, ushort_t* __restrict__ vt) {
    __shared__ float t[64][65];
    const int tid = threadIdx.x;
    const int bh = blockIdx.z;
    const int s0 = blockIdx.x << 6;
    const int d0 = blockIdx.y << 6;
    const float* src = v + ((size_t)bh * SEQ + s0) * HD + d0;
    const int rr = tid >> 4;
    const int cc = (tid & 15) << 2;
#pragma unroll
    for (int i = 0; i < 4; i++) {
        float4 x = *(const float4*)(src + (size_t)(i * 16 + rr) * HD + cc);
        t[i * 16 + rr][cc] = x.x;
        t[i * 16 + rr][cc + 1] = x.y;
        t[i * 16 + rr][cc + 2] = x.z;
        t[i * 16 + rr][cc + 3] = x.w;
    }
    __syncthreads();
    const int dr = tid >> 2;
    const int sc_ = (tid & 3) << 4;
    ushort_t* dst = vt + ((size_t)bh * HD + d0 + dr) * SEQ + s0 + sc_;
    u16x8 o0, o1;
#pragma unroll
    for (int u = 0; u < 8; u++) o0[u] = bf16r(t[sc_ + u][dr]);
#pragma unroll
    for (int u = 0; u < 8; u++) o1[u] = bf16r(t[sc_ + 8 + u][dr]);
    *(u16x8*)dst = o0;
    *(u16x8*)(dst + 8) = o1;
}

// ==================== MFMA flash attention v4 ================================
__global__ __launch_bounds__(256, 2)
void k_flash_mfma(const ushort_t* __restrict__ Qb, const ushort_t* __restrict__ Kb,
                  const ushort_t* __restrict__ Vt,
                  ushort_t* __restrict__ ch, ushort_t* __restrict__ cl) {
    __shared__ ushort_t KV[128 * 136];
    __shared__ ushort_t Ps[128 * 136];
    const int tid = threadIdx.x;
    const int lane = tid & 63;
    const int w = tid >> 6;
    const int quad = lane >> 4;
    const int l15 = lane & 15;
    const int bi = blockIdx.x;
    const int bh = bi & 31;              // XCD swizzle: bh%8 == XCD id
    const int qt = bi >> 5;              // 0..15 (128 q rows each)
    const ushort_t* Qg = Qb + ((size_t)bh * SEQ + ((size_t)qt << 7)) * HD;
    const ushort_t* Kg = Kb + (size_t)bh * SEQ * HD;
    const ushort_t* Vg = Vt + (size_t)bh * HD * SEQ;

    // persistent Q fragments (B-operand): rows w*32+qi*16+l15, k = ks*32+quad*8
    bf16x8 qf[2][4];
#pragma unroll
    for (int qi = 0; qi < 2; qi++)
#pragma unroll
        for (int ks = 0; ks < 4; ks++)
            qf[qi][ks] = *(const bf16x8*)(Qg + (size_t)(w * 32 + qi * 16 + l15) * HD + ks * 32 + quad * 8);

    const int sr = tid >> 4;            // staging row 0..15
    const int sc8 = (tid & 15) << 3;    // staging col (8 elems = 16B)

    // prefetch chunk 0 K and V^T into registers
    u16x8 Kreg[8], Vreg[8];
#pragma unroll
    for (int i = 0; i < 8; i++)
        Kreg[i] = *(const u16x8*)(Kg + (size_t)(i * 16 + sr) * HD + sc8);
#pragma unroll
    for (int i = 0; i < 8; i++)
        Vreg[i] = *(const u16x8*)(Vg + (size_t)(i * 16 + sr) * SEQ + sc8);

    f32x4 acc[2][8];
#pragma unroll
    for (int qi = 0; qi < 2; qi++)
#pragma unroll
        for (int d = 0; d < 8; d++) acc[qi][d] = (f32x4){0.f, 0.f, 0.f, 0.f};
    float lp[2] = {0.f, 0.f};

    for (int kt = 0; kt < SEQ; kt += 128) {
        const int np = kt + 128;
        __syncthreads();                // prev PV reads of KV done
#pragma unroll
        for (int i = 0; i < 8; i++)     // stage K_i; refill Kreg = K_{i+1}
            *(u16x8*)&KV[(i * 16 + sr) * 136 + sc8] = Kreg[i];
        if (np < SEQ) {
#pragma unroll
            for (int i = 0; i < 8; i++)
                Kreg[i] = *(const u16x8*)(Kg + (size_t)(np + i * 16 + sr) * HD + sc8);
        }
        __syncthreads();

        // ---- scores transposed: sc[qi][j] = K(16 rows) x Q(16 rows)^T ----
        f32x4 sc[2][8];
#pragma unroll
        for (int qi = 0; qi < 2; qi++)
#pragma unroll
            for (int j = 0; j < 8; j++) sc[qi][j] = (f32x4){0.f, 0.f, 0.f, 0.f};
#pragma unroll
        for (int ks = 0; ks < 4; ks++) {
#pragma unroll
            for (int jh = 0; jh < 2; jh++) {
                bf16x8 kf[4];
#pragma unroll
                for (int j = 0; j < 4; j++)
                    kf[j] = *(const bf16x8*)&KV[((jh * 4 + j) * 16 + l15) * 136 + ks * 32 + quad * 8];
#pragma unroll
                for (int qi = 0; qi < 2; qi++)
#pragma unroll
                    for (int j = 0; j < 4; j++)
                        sc[qi][jh * 4 + j] = __builtin_amdgcn_mfma_f32_16x16x32_bf16(
                            kf[j], qf[qi][ks], sc[qi][jh * 4 + j], 0, 0, 0);
            }
        }

        // ---- p = exp(score); accumulate l; write P (8B contiguous) ----
#pragma unroll
        for (int qi = 0; qi < 2; qi++) {
            const int prow = (w * 32 + qi * 16 + l15) * 136 + quad * 4;
#pragma unroll
            for (int j = 0; j < 8; j++) {
                float p0 = __expf(sc[qi][j][0]);
                float p1 = __expf(sc[qi][j][1]);
                float p2 = __expf(sc[qi][j][2]);
                float p3 = __expf(sc[qi][j][3]);
                lp[qi] += (p0 + p1) + (p2 + p3);
                __hip_bfloat162 lo2 = __float22bfloat162_rn({p0, p1});
                __hip_bfloat162 hi2 = __float22bfloat162_rn({p2, p3});
                uint2 pk = make_uint2(*(u32*)&lo2, *(u32*)&hi2);
                *(uint2*)&Ps[prow + j * 16] = pk;
            }
        }
        __syncthreads();                // kf reads done + Ps visible
#pragma unroll
        for (int i = 0; i < 8; i++)     // stage V_i; refill Vreg = V_{i+1}
            *(u16x8*)&KV[(i * 16 + sr) * 136 + sc8] = Vreg[i];
        if (np < SEQ) {
#pragma unroll
            for (int i = 0; i < 8; i++)
                Vreg[i] = *(const u16x8*)(Vg + (size_t)(i * 16 + sr) * SEQ + np + sc8);
        }
        __syncthreads();

        // ---- PV transposed: acc[qi][db] = V^T(16 d-rows) x P^T ----
#pragma unroll
        for (int ks = 0; ks < 4; ks++) {
            bf16x8 pf[2];
#pragma unroll
            for (int qi = 0; qi < 2; qi++)
                pf[qi] = *(const bf16x8*)&Ps[(w * 32 + qi * 16 + l15) * 136 + ks * 32 + quad * 8];
#pragma unroll
            for (int db = 0; db < 8; db++) {
                bf16x8 vf = *(const bf16x8*)&KV[(db * 16 + l15) * 136 + ks * 32 + quad * 8];
#pragma unroll
                for (int qi = 0; qi < 2; qi++)
                    acc[qi][db] = __builtin_amdgcn_mfma_f32_16x16x32_bf16(vf, pf[qi], acc[qi][db], 0, 0, 0);
            }
        }
    }

    // ---- epilogue: l-reduce, normalize, re-layout via Ps, coalesced store ----
    float inv[2];
#pragma unroll
    for (int qi = 0; qi < 2; qi++) {
        float l = lp[qi];
        l += __shfl_xor(l, 16);
        l += __shfl_xor(l, 32);
        inv[qi] = 1.0f / l;
    }
    const size_t obase = ((size_t)bh * SEQ + ((size_t)qt << 7)) * HD;

    __syncthreads();                    // final PV pf reads of Ps done
    // hi pass
#pragma unroll
    for (int qi = 0; qi < 2; qi++)
#pragma unroll
        for (int db = 0; db < 8; db++) {
            ushort4 hh;
            ushort_t dum;
            split1(acc[qi][db][0] * inv[qi], hh.x, dum);
            split1(acc[qi][db][1] * inv[qi], hh.y, dum);
            split1(acc[qi][db][2] * inv[qi], hh.z, dum);
            split1(acc[qi][db][3] * inv[qi], hh.w, dum);
            *(ushort4*)&Ps[(w * 32 + qi * 16 + l15) * 136 + db * 16 + quad * 4] = hh;
        }
    __syncthreads();
#pragma unroll
    for (int t = 0; t < 8; t++) {
        int c = t * 256 + tid;
        int row = c >> 4, col8 = (c & 15) << 3;
        *(u16x8*)&ch[obase + (size_t)row * HD + col8] = *(const u16x8*)&Ps[row * 136 + col8];
    }
    __syncthreads();
    // lo pass
#pragma unroll
    for (int qi = 0; qi < 2; qi++)
#pragma unroll
        for (int db = 0; db < 8; db++) {
            ushort4 ll;
            ushort_t dum;
            split1(acc[qi][db][0] * inv[qi], dum, ll.x);
            split1(acc[qi][db][1] * inv[qi], dum, ll.y);
            split1(acc[qi][db][2] * inv[qi], dum, ll.z);
            split1(acc[qi][db][3] * inv[qi], dum, ll.w);
            *(ushort4*)&Ps[(w * 32 + qi * 16 + l15) * 136 + db * 16 + quad * 4] = ll;
        }
    __syncthreads();
#pragma unroll
    for (int t = 0; t < 8; t++) {
        int c = t * 256 + tid;
        int row = c >> 4, col8 = (c & 15) << 3;
        *(u16x8*)&cl[obase + (size_t)row * HD + col8] = *(const u16x8*)&Ps[row * 136 + col8];
    }
}

// ==================== launch =================================================
extern "C" void kernel_launch(void* const* d_in, const int* in_sizes, int n_in,
                              void* d_out, int out_size, void* d_ws, size_t ws_size,
                              hipStream_t stream) {
    const float* X  = (const float*)d_in[0];
    const float* Wq = (const float*)d_in[1];
    const float* bq = (const float*)d_in[2];
    const float* Wk = (const float*)d_in[3];
    const float* bk = (const float*)d_in[4];
    const float* Wv = (const float*)d_in[5];
    const float* bv = (const float*)d_in[6];
    const float* Wo = (const float*)d_in[7];
    const float* bo = (const float*)d_in[8];
    float* out = (float*)d_out;

    const size_t QS = (size_t)NB * NH * SEQ * HD;   // 8,388,608 elems
    const size_t WS = (size_t)HIDDEN * HIDDEN;      // 4,194,304 elems
    float* q_ws = (float*)d_ws;
    float* k_ws = q_ws + QS;
    float* v_ws = k_ws + QS;
    float* cost = v_ws + QS;
    float* sint = cost + (size_t)SEQ * 64;
    ushort_t* Xh = (ushort_t*)(sint + (size_t)SEQ * 64);  // -> Qb after QKV
    ushort_t* Wh0 = Xh + QS;
    ushort_t* Wh1 = Wh0 + WS;
    ushort_t* Wh2 = Wh1 + WS;
    ushort_t* Woh = Wh2 + WS;
    ushort_t* Wol = Woh + WS;
    ushort_t* Kb  = Wol + WS;
    ushort_t* Vtb = Kb + QS;
    ushort_t* ctxh = (ushort_t*)q_ws;                     // blocked ctx over dead q_ws
    ushort_t* ctxl = ctxh + QS;

    k_rope_tables<<<(SEQ * 64) / 256, 256, 0, stream>>>(cost, sint);

    k_cvt_all<<<(XG + 3 * WG) / 256, 256, 0, stream>>>(
        (const float4*)X, (const float4*)Wq, (const float4*)Wk, (const float4*)Wv,
        (ushort4*)Xh, (ushort4*)Wh0, (ushort4*)Wh1, (ushort4*)Wh2);
    k_split<<<WS / 4 / 256, 256, 0, stream>>>((const float4*)Wo, (ushort4*)Woh, (ushort4*)Wol);

    k_gemm_qkv8<<<384, 512, 0, stream>>>(Xh, Wh0, Wh1, Wh2, bq, bk, bv,
                                         q_ws, k_ws, v_ws);

    ushort_t* Qbb = Xh;   // X bf16 dead after QKV GEMM
    k_rope_pack<<<(NB * NH * SEQ * 64) / 256, 256, 0, stream>>>(q_ws, k_ws, cost, sint, Qbb, Kb);
    k_vpack<<<dim3(SEQ / 64, HD / 64, NB * NH), 256, 0, stream>>>(v_ws, Vtb);

    k_flash_mfma<<<512, 256, 0, stream>>>(Qbb, Kb, Vtb, ctxh, ctxl);

    k_gemm_o<<<dim3(32, 16), 256, 0, stream>>>(ctxh, ctxl, Woh, Wol, bo, out);
}